// Round 1
// baseline (355.966 us; speedup 1.0000x reference)
//
#include <hip/hip_runtime.h>

// LinearSelfAttention: out = rot(q) @ (rot(k)^T @ (w*v)), per-batch, fp16 MFMA.
//
// Layout tricks:
//  * Wq/Wk rows pre-permuted interleaved (2j <- j, 2j+1 <- j+256) so rotary
//    pairs are adjacent columns -> adjacent MFMA lanes -> __shfl_xor(.,1).
//    The d-permutation is identical for q and k and d is contracted, so the
//    final result is unchanged.
//  * QKV epilogue transposes k and v tiles through LDS: krT[b][d][n],
//    vwT[b][e][n], so the kv GEMM (K=n) and out GEMM (K=d, via kvT[e][d])
//    have K contiguous in both operands -> single ds_read_b128 per fragment.
//
// ws layout (needs ~133.5 MiB):
//   phi_h  [32768][512] f16   @ 0          (33,554,432 B)
//   wcat   [1536][512]  f16   @ 33,554,432 ( 1,572,864 B)  rows: q' k' v
//   bcat   [1536]       f32   @ 35,127,296 (     6,144 B)
//   qr     [32768][512] f16   @ 35,133,440 (33,554,432 B)
//   krT    [8][512][4096] f16 @ 68,687,872 (33,554,432 B)
//   vwT    [8][512][4096] f16 @ 102,242,304(33,554,432 B)
//   kvT    [8][512][512] f16  @ 135,796,736( 4,194,304 B)  -> end 139,991,040

typedef _Float16 f16x8 __attribute__((ext_vector_type(8)));
typedef _Float16 f16x4 __attribute__((ext_vector_type(4)));
typedef float f32x4 __attribute__((ext_vector_type(4)));

#define LSTR 40   // LDS row stride for 32-wide K tiles (+8 pad, keeps 16B align)

// ---------------------------------------------------------------- prep ----
__global__ __launch_bounds__(256) void convert_phi(const float* __restrict__ phi,
                                                   _Float16* __restrict__ phi_h) {
    int i = (blockIdx.x * 256 + threadIdx.x) * 4;
    float4 v = *(const float4*)(phi + i);
    f16x4 o = {(_Float16)v.x, (_Float16)v.y, (_Float16)v.z, (_Float16)v.w};
    *(f16x4*)(phi_h + i) = o;
}

__global__ __launch_bounds__(256) void pack_w(
    const float* __restrict__ Wq, const float* __restrict__ Wk,
    const float* __restrict__ Wv, const float* __restrict__ bq,
    const float* __restrict__ bk, const float* __restrict__ bv,
    _Float16* __restrict__ wcat, float* __restrict__ bcat) {
    int j = blockIdx.x;            // 0..1535 output row
    int reg = j >> 9, jr = j & 511;
    const float* W; const float* bias;
    if (reg == 0)      { W = Wq; bias = bq; }
    else if (reg == 1) { W = Wk; bias = bk; }
    else               { W = Wv; bias = bv; }
    int d = (reg < 2) ? ((jr & 1) ? (jr >> 1) + 256 : (jr >> 1)) : jr;
    for (int i = threadIdx.x; i < 512; i += 256)
        wcat[j * 512 + i] = (_Float16)W[d * 512 + i];
    if (threadIdx.x == 0) bcat[j] = bias[d];
}

// ------------------------------------------------------------ QKV GEMM ----
// C[32768][1536] = phi_h @ wcat^T, tile 128x64, BK=32, 4 waves (2x2), each
// wave 64x32 = 4x2 subtiles of 16x16. Epilogue: q->rotary->qr (natural),
// k->rotary->LDS transpose->krT, v->weights->LDS transpose->vwT.
__global__ __launch_bounds__(256) void qkv_kernel(
    const _Float16* __restrict__ phi_h, const _Float16* __restrict__ wcat,
    const float* __restrict__ bcat, const float* __restrict__ coords,
    const float* __restrict__ weights, const float* __restrict__ Wrot,
    _Float16* __restrict__ qr, _Float16* __restrict__ krT,
    _Float16* __restrict__ vwT) {
    __shared__ _Float16 As[128 * LSTR];
    __shared__ _Float16 Bs[64 * LSTR];
    __shared__ _Float16 Ts[64 * 136];   // transpose buffer [col][row], pad 8

    const int tid = threadIdx.x;
    const int lane = tid & 63, wave = tid >> 6;
    const int quad = lane >> 4, l16 = lane & 15;
    const int wm = (wave >> 1) * 64, wn = (wave & 1) * 32;
    const int m0 = blockIdx.y * 128;      // row tile (over B*N)
    const int c0 = blockIdx.x * 64;       // col tile (over 1536)

    f32x4 acc[4][2] = {};

    const int srow = tid >> 2, skk = (tid & 3) * 8;
    for (int k0 = 0; k0 < 512; k0 += 32) {
        *(f16x8*)&As[srow * LSTR + skk] =
            *(const f16x8*)&phi_h[(m0 + srow) * 512 + k0 + skk];
        *(f16x8*)&As[(srow + 64) * LSTR + skk] =
            *(const f16x8*)&phi_h[(m0 + srow + 64) * 512 + k0 + skk];
        *(f16x8*)&Bs[srow * LSTR + skk] =
            *(const f16x8*)&wcat[(c0 + srow) * 512 + k0 + skk];
        __syncthreads();
        f16x8 af[4], bf[2];
        #pragma unroll
        for (int mi = 0; mi < 4; mi++)
            af[mi] = *(f16x8*)&As[(wm + mi * 16 + l16) * LSTR + quad * 8];
        #pragma unroll
        for (int ni = 0; ni < 2; ni++)
            bf[ni] = *(f16x8*)&Bs[(wn + ni * 16 + l16) * LSTR + quad * 8];
        #pragma unroll
        for (int mi = 0; mi < 4; mi++)
            #pragma unroll
            for (int ni = 0; ni < 2; ni++)
                acc[mi][ni] = __builtin_amdgcn_mfma_f32_16x16x32_f16(
                    af[mi], bf[ni], acc[mi][ni], 0, 0, 0);
        __syncthreads();
    }

    const int region = c0 >> 9;   // 0=q, 1=k, 2=v (tile never straddles)
    const float qscale = 0.04419417382415922f;  // 1/sqrt(512)

    float bias[2], w0[2], w1[2], w2[2];
    #pragma unroll
    for (int ni = 0; ni < 2; ni++) {
        int gc = c0 + wn + ni * 16 + l16;
        bias[ni] = bcat[gc];
        if (region < 2) {
            int jp = (gc & 511) >> 1;
            w0[ni] = Wrot[jp * 3];
            w1[ni] = Wrot[jp * 3 + 1];
            w2[ni] = Wrot[jp * 3 + 2];
        }
    }

    if (region == 0) {
        // q: rotary + scale, natural store qr[gm][d']
        #pragma unroll
        for (int mi = 0; mi < 4; mi++)
            #pragma unroll
            for (int r = 0; r < 4; r++) {
                int gm = m0 + wm + mi * 16 + quad * 4 + r;
                float x = coords[gm * 3], y = coords[gm * 3 + 1], z = coords[gm * 3 + 2];
                #pragma unroll
                for (int ni = 0; ni < 2; ni++) {
                    float val = (acc[mi][ni][r] + bias[ni]) * qscale;
                    float part = __shfl_xor(val, 1);
                    float ph = x * w0[ni] + y * w1[ni] + z * w2[ni];
                    float sv, cv; __sincosf(ph, &sv, &cv);
                    // even lane holds a_j, odd lane holds b_j (same pair jp)
                    float res = (l16 & 1) ? (part * sv + val * cv)
                                          : (val * cv - part * sv);
                    qr[gm * 512 + (c0 + wn + ni * 16 + l16)] = (_Float16)res;
                }
            }
    } else {
        // k: rotary; v: *weights. Both -> LDS transpose -> [b][col][n] store.
        #pragma unroll
        for (int mi = 0; mi < 4; mi++)
            #pragma unroll
            for (int r = 0; r < 4; r++) {
                int row = wm + mi * 16 + quad * 4 + r;   // block-local 0..127
                int gm = m0 + row;
                if (region == 1) {
                    float x = coords[gm * 3], y = coords[gm * 3 + 1], z = coords[gm * 3 + 2];
                    #pragma unroll
                    for (int ni = 0; ni < 2; ni++) {
                        float val = acc[mi][ni][r] + bias[ni];
                        float part = __shfl_xor(val, 1);
                        float ph = x * w0[ni] + y * w1[ni] + z * w2[ni];
                        float sv, cv; __sincosf(ph, &sv, &cv);
                        float res = (l16 & 1) ? (part * sv + val * cv)
                                              : (val * cv - part * sv);
                        Ts[(wn + ni * 16 + l16) * 136 + row] = (_Float16)res;
                    }
                } else {
                    float wgt = weights[gm];
                    #pragma unroll
                    for (int ni = 0; ni < 2; ni++) {
                        float val = (acc[mi][ni][r] + bias[ni]) * wgt;
                        Ts[(wn + ni * 16 + l16) * 136 + row] = (_Float16)val;
                    }
                }
            }
        __syncthreads();
        _Float16* dst = (region == 1) ? krT : vwT;
        const int b = m0 >> 12, n0 = m0 & 4095, cb = c0 & 511;
        // 64 cols x 128 rows = 1024 vecs of 8 f16; 4 per thread
        for (int i = tid; i < 1024; i += 256) {
            int colv = i >> 4, nv = (i & 15) * 8;
            f16x8 vdat = *(f16x8*)&Ts[colv * 136 + nv];
            *(f16x8*)&dst[((size_t)b * 512 + cb + colv) * 4096 + n0 + nv] = vdat;
        }
    }
}

// ------------------------------------------------------------- kv GEMM ----
// kvT[b][e][d] = sum_n vwT[b][e][n] * krT[b][d][n]; tile 64x64, BK=32,
// 4 waves (2x2), each 32x32.
__global__ __launch_bounds__(256) void kv_kernel(
    const _Float16* __restrict__ vwT, const _Float16* __restrict__ krT,
    _Float16* __restrict__ kvT) {
    __shared__ _Float16 As[64 * LSTR];
    __shared__ _Float16 Bs[64 * LSTR];
    const int tid = threadIdx.x, lane = tid & 63, wave = tid >> 6;
    const int quad = lane >> 4, l16 = lane & 15;
    const int wm = (wave >> 1) * 32, wn = (wave & 1) * 32;
    const int d0 = blockIdx.x * 64, e0 = blockIdx.y * 64, b = blockIdx.z;
    const size_t base = (size_t)b * 512 * 4096;
    f32x4 acc[2][2] = {};
    const int srow = tid >> 2, skk = (tid & 3) * 8;
    for (int k0 = 0; k0 < 4096; k0 += 32) {
        *(f16x8*)&As[srow * LSTR + skk] =
            *(const f16x8*)&vwT[base + (size_t)(e0 + srow) * 4096 + k0 + skk];
        *(f16x8*)&Bs[srow * LSTR + skk] =
            *(const f16x8*)&krT[base + (size_t)(d0 + srow) * 4096 + k0 + skk];
        __syncthreads();
        f16x8 af[2], bf[2];
        #pragma unroll
        for (int mi = 0; mi < 2; mi++)
            af[mi] = *(f16x8*)&As[(wm + mi * 16 + l16) * LSTR + quad * 8];
        #pragma unroll
        for (int ni = 0; ni < 2; ni++)
            bf[ni] = *(f16x8*)&Bs[(wn + ni * 16 + l16) * LSTR + quad * 8];
        #pragma unroll
        for (int mi = 0; mi < 2; mi++)
            #pragma unroll
            for (int ni = 0; ni < 2; ni++)
                acc[mi][ni] = __builtin_amdgcn_mfma_f32_16x16x32_f16(
                    af[mi], bf[ni], acc[mi][ni], 0, 0, 0);
        __syncthreads();
    }
    #pragma unroll
    for (int mi = 0; mi < 2; mi++)
        #pragma unroll
        for (int ni = 0; ni < 2; ni++)
            #pragma unroll
            for (int r = 0; r < 4; r++) {
                int e = e0 + wm + mi * 16 + quad * 4 + r;
                int d = d0 + wn + ni * 16 + l16;
                kvT[(size_t)b * 262144 + e * 512 + d] = (_Float16)acc[mi][ni][r];
            }
}

// ------------------------------------------------------------ out GEMM ----
// out[gm][e] = sum_d qr[gm][d] * kvT[b][e][d]; tile 128x64, BK=32.
__global__ __launch_bounds__(256) void out_kernel(
    const _Float16* __restrict__ qr, const _Float16* __restrict__ kvT,
    float* __restrict__ out) {
    __shared__ _Float16 As[128 * LSTR];
    __shared__ _Float16 Bs[64 * LSTR];
    const int tid = threadIdx.x, lane = tid & 63, wave = tid >> 6;
    const int quad = lane >> 4, l16 = lane & 15;
    const int wm = (wave >> 1) * 64, wn = (wave & 1) * 32;
    const int m0 = blockIdx.y * 128, e0 = blockIdx.x * 64;
    const int b = m0 >> 12;
    f32x4 acc[4][2] = {};
    const int srow = tid >> 2, skk = (tid & 3) * 8;
    for (int k0 = 0; k0 < 512; k0 += 32) {
        *(f16x8*)&As[srow * LSTR + skk] =
            *(const f16x8*)&qr[(m0 + srow) * 512 + k0 + skk];
        *(f16x8*)&As[(srow + 64) * LSTR + skk] =
            *(const f16x8*)&qr[(m0 + srow + 64) * 512 + k0 + skk];
        *(f16x8*)&Bs[srow * LSTR + skk] =
            *(const f16x8*)&kvT[(size_t)b * 262144 + (e0 + srow) * 512 + k0 + skk];
        __syncthreads();
        f16x8 af[4], bf[2];
        #pragma unroll
        for (int mi = 0; mi < 4; mi++)
            af[mi] = *(f16x8*)&As[(wm + mi * 16 + l16) * LSTR + quad * 8];
        #pragma unroll
        for (int ni = 0; ni < 2; ni++)
            bf[ni] = *(f16x8*)&Bs[(wn + ni * 16 + l16) * LSTR + quad * 8];
        #pragma unroll
        for (int mi = 0; mi < 4; mi++)
            #pragma unroll
            for (int ni = 0; ni < 2; ni++)
                acc[mi][ni] = __builtin_amdgcn_mfma_f32_16x16x32_f16(
                    af[mi], bf[ni], acc[mi][ni], 0, 0, 0);
        __syncthreads();
    }
    #pragma unroll
    for (int mi = 0; mi < 4; mi++)
        #pragma unroll
        for (int ni = 0; ni < 2; ni++)
            #pragma unroll
            for (int r = 0; r < 4; r++) {
                int gm = m0 + wm + mi * 16 + quad * 4 + r;
                int e = e0 + wn + ni * 16 + l16;
                out[(size_t)gm * 512 + e] = acc[mi][ni][r];
            }
}

// -------------------------------------------------------------- launch ----
extern "C" void kernel_launch(void* const* d_in, const int* in_sizes, int n_in,
                              void* d_out, int out_size, void* d_ws, size_t ws_size,
                              hipStream_t stream) {
    const float* phi     = (const float*)d_in[0];
    const float* coords  = (const float*)d_in[1];
    const float* weights = (const float*)d_in[2];
    const float* Wq      = (const float*)d_in[3];
    const float* bq      = (const float*)d_in[4];
    const float* Wk      = (const float*)d_in[5];
    const float* bk      = (const float*)d_in[6];
    const float* Wv      = (const float*)d_in[7];
    const float* bv      = (const float*)d_in[8];
    const float* Wrot    = (const float*)d_in[9];
    float* out = (float*)d_out;

    char* ws = (char*)d_ws;
    _Float16* phi_h = (_Float16*)(ws);
    _Float16* wcat  = (_Float16*)(ws + 33554432);
    float*    bcat  = (float*)   (ws + 35127296);
    _Float16* qr    = (_Float16*)(ws + 35133440);
    _Float16* krT   = (_Float16*)(ws + 68687872);
    _Float16* vwT   = (_Float16*)(ws + 102242304);
    _Float16* kvT   = (_Float16*)(ws + 135796736);  // end: 139,991,040 B

    convert_phi<<<16384, 256, 0, stream>>>(phi, phi_h);
    pack_w<<<1536, 256, 0, stream>>>(Wq, Wk, Wv, bq, bk, bv, wcat, bcat);
    qkv_kernel<<<dim3(24, 256), 256, 0, stream>>>(phi_h, wcat, bcat, coords,
                                                  weights, Wrot, qr, krT, vwT);
    kv_kernel<<<dim3(8, 8, 8), 256, 0, stream>>>(vwT, krT, kvT);
    out_kernel<<<dim3(8, 256), 256, 0, stream>>>(qr, kvT, out);
}

// Round 2
// 326.320 us; speedup vs baseline: 1.0909x; 1.0909x over previous
//
#include <hip/hip_runtime.h>

// LinearSelfAttention: out = rot(q) @ (rot(k)^T @ (w*v)), fp16 MFMA, m97-style
// 128x128 tiles with global_load_lds width=16 staging.
//
// ws layout (~133.5 MiB):
//   phi_h  [32768][512] f16   @ 0            (33,554,432 B)  } kvp fp32 aliases
//   wcat   [1536][512]  f16   @ 33,554,432   ( 1,572,864 B)    phi_h after qkv
//   bcat   [1536]       f32   @ 35,127,296   (     6,144 B)
//   qr     [32768][512] f16   @ 35,133,440   (33,554,432 B)
//   krT    [8][512][4096] f16 @ 68,687,872   (33,554,432 B)
//   vwT    [8][512][4096] f16 @ 102,242,304  (33,554,432 B)
//   kvT    [8][512][512] f16  @ 135,796,736  ( 4,194,304 B)

typedef _Float16 f16x8 __attribute__((ext_vector_type(8)));
typedef _Float16 f16x4 __attribute__((ext_vector_type(4)));
typedef float f32x4 __attribute__((ext_vector_type(4)));

__device__ __forceinline__ void gl_lds16(const void* g, void* l) {
    __builtin_amdgcn_global_load_lds(
        (const __attribute__((address_space(1))) void*)g,
        (__attribute__((address_space(3))) void*)l, 16, 0, 0);
}

// ---------------------------------------------------------------- prep ----
__global__ __launch_bounds__(256) void convert_phi(const float* __restrict__ phi,
                                                   _Float16* __restrict__ phi_h) {
    int i = (blockIdx.x * 256 + threadIdx.x) * 4;
    float4 v = *(const float4*)(phi + i);
    f16x4 o = {(_Float16)v.x, (_Float16)v.y, (_Float16)v.z, (_Float16)v.w};
    *(f16x4*)(phi_h + i) = o;
}

__global__ __launch_bounds__(256) void pack_w(
    const float* __restrict__ Wq, const float* __restrict__ Wk,
    const float* __restrict__ Wv, const float* __restrict__ bq,
    const float* __restrict__ bk, const float* __restrict__ bv,
    _Float16* __restrict__ wcat, float* __restrict__ bcat) {
    int j = blockIdx.x;            // 0..1535 output row
    int reg = j >> 9, jr = j & 511;
    const float* W; const float* bias;
    if (reg == 0)      { W = Wq; bias = bq; }
    else if (reg == 1) { W = Wk; bias = bk; }
    else               { W = Wv; bias = bv; }
    int d = (reg < 2) ? ((jr & 1) ? (jr >> 1) + 256 : (jr >> 1)) : jr;
    for (int i = threadIdx.x; i < 512; i += 256)
        wcat[j * 512 + i] = (_Float16)W[d * 512 + i];
    if (threadIdx.x == 0) bcat[j] = bias[d];
}

// ------------------------------------------------------------ QKV GEMM ----
// C[32768][1536] = phi_h @ wcat^T, tile 128x128, BK=32, 4 waves 2x2, each
// wave 64x64 (4x4 16x16 subtiles). Staging via global_load_lds dwordx4.
__global__ __launch_bounds__(256) void qkv_kernel(
    const _Float16* __restrict__ phi_h, const _Float16* __restrict__ wcat,
    const float* __restrict__ bcat, const float* __restrict__ coords,
    const float* __restrict__ weights, const float* __restrict__ Wrot,
    _Float16* __restrict__ qr, _Float16* __restrict__ krT,
    _Float16* __restrict__ vwT) {
    __shared__ __align__(16) char smem[34816];          // Ts 128x136 f16
    _Float16* As = (_Float16*)smem;                     // 128x32 (8 KB)
    _Float16* Bs = (_Float16*)(smem + 8192);            // 128x32 (8 KB)
    _Float16* Ts = (_Float16*)smem;                     // aliases, post-loop

    const int tid = threadIdx.x;
    const int lane = tid & 63, wave = tid >> 6;
    const int quad = lane >> 4, l16 = lane & 15;
    const int wm = (wave >> 1) * 64, wn = (wave & 1) * 64;
    const int m0 = blockIdx.y * 128;      // row tile (over B*N)
    const int c0 = blockIdx.x * 128;      // col tile (over 1536)

    // staging coords: chunk = 16 rows of 64 B; lane -> row chunk*16+lane/4,
    // 16B segment lane%4. LDS dest = chunk base + lane*16 (HW).
    const int ca = wave * 2;                 // this wave's chunks (A: ca,ca+1)
    const int srow = lane >> 2, sseg = (lane & 3) * 8;

    f32x4 acc[4][4] = {};

    for (int k0 = 0; k0 < 512; k0 += 32) {
        #pragma unroll
        for (int c = 0; c < 2; c++) {
            int chunk = ca + c;
            int row = chunk * 16 + srow;
            gl_lds16(&phi_h[(m0 + row) * 512 + k0 + sseg], &As[chunk * 512]);
            gl_lds16(&wcat[(c0 + row) * 512 + k0 + sseg], &Bs[chunk * 512]);
        }
        __syncthreads();
        f16x8 af[4], bf[4];
        #pragma unroll
        for (int mi = 0; mi < 4; mi++)
            af[mi] = *(f16x8*)&As[(wm + mi * 16 + l16) * 32 + quad * 8];
        #pragma unroll
        for (int ni = 0; ni < 4; ni++)
            bf[ni] = *(f16x8*)&Bs[(wn + ni * 16 + l16) * 32 + quad * 8];
        #pragma unroll
        for (int mi = 0; mi < 4; mi++)
            #pragma unroll
            for (int ni = 0; ni < 4; ni++)
                acc[mi][ni] = __builtin_amdgcn_mfma_f32_16x16x32_f16(
                    af[mi], bf[ni], acc[mi][ni], 0, 0, 0);
        __syncthreads();
    }

    const int region = c0 >> 9;   // 0=q, 1=k, 2=v (128 | 512: never straddles)
    const float qscale = 0.04419417382415922f;  // 1/sqrt(512)

    float bias[4], w0[4], w1[4], w2[4];
    #pragma unroll
    for (int ni = 0; ni < 4; ni++) {
        int gc = c0 + wn + ni * 16 + l16;
        bias[ni] = bcat[gc];
        if (region < 2) {
            int jp = (gc & 511) >> 1;
            w0[ni] = Wrot[jp * 3];
            w1[ni] = Wrot[jp * 3 + 1];
            w2[ni] = Wrot[jp * 3 + 2];
        }
    }

    if (region == 0) {
        // q: rotary + scale -> Ts[row][col] -> coalesced qr store
        #pragma unroll
        for (int mi = 0; mi < 4; mi++)
            #pragma unroll
            for (int r = 0; r < 4; r++) {
                int row = wm + mi * 16 + quad * 4 + r;
                int gm = m0 + row;
                float x = coords[gm * 3], y = coords[gm * 3 + 1], z = coords[gm * 3 + 2];
                #pragma unroll
                for (int ni = 0; ni < 4; ni++) {
                    float val = (acc[mi][ni][r] + bias[ni]) * qscale;
                    float part = __shfl_xor(val, 1);
                    float ph = x * w0[ni] + y * w1[ni] + z * w2[ni];
                    float sv, cv; __sincosf(ph, &sv, &cv);
                    float res = (l16 & 1) ? (part * sv + val * cv)
                                          : (val * cv - part * sv);
                    Ts[row * 136 + wn + ni * 16 + l16] = (_Float16)res;
                }
            }
        __syncthreads();
        for (int i = tid; i < 2048; i += 256) {
            int row = i >> 4, cv = (i & 15) * 8;
            *(f16x8*)&qr[(m0 + row) * 512 + c0 + cv] = *(f16x8*)&Ts[row * 136 + cv];
        }
    } else {
        // k: rotary; v: *weights. -> Ts[col][row] -> coalesced [b][col][n]
        #pragma unroll
        for (int mi = 0; mi < 4; mi++)
            #pragma unroll
            for (int r = 0; r < 4; r++) {
                int row = wm + mi * 16 + quad * 4 + r;
                int gm = m0 + row;
                if (region == 1) {
                    float x = coords[gm * 3], y = coords[gm * 3 + 1], z = coords[gm * 3 + 2];
                    #pragma unroll
                    for (int ni = 0; ni < 4; ni++) {
                        float val = acc[mi][ni][r] + bias[ni];
                        float part = __shfl_xor(val, 1);
                        float ph = x * w0[ni] + y * w1[ni] + z * w2[ni];
                        float sv, cv; __sincosf(ph, &sv, &cv);
                        float res = (l16 & 1) ? (part * sv + val * cv)
                                              : (val * cv - part * sv);
                        Ts[(wn + ni * 16 + l16) * 136 + row] = (_Float16)res;
                    }
                } else {
                    float wgt = weights[gm];
                    #pragma unroll
                    for (int ni = 0; ni < 4; ni++) {
                        float val = (acc[mi][ni][r] + bias[ni]) * wgt;
                        Ts[(wn + ni * 16 + l16) * 136 + row] = (_Float16)val;
                    }
                }
            }
        __syncthreads();
        _Float16* dst = (region == 1) ? krT : vwT;
        const int b = m0 >> 12, n0 = m0 & 4095, cb = c0 & 511;
        for (int i = tid; i < 2048; i += 256) {
            int col = i >> 4, rv = (i & 15) * 8;
            *(f16x8*)&dst[((size_t)b * 512 + cb + col) * 4096 + n0 + rv] =
                *(f16x8*)&Ts[col * 136 + rv];
        }
    }
}

// ------------------------------------------------------------- kv GEMM ----
// kvp[s][b][e][d] = sum_{n in split s} vwT[b][e][n]*krT[b][d][n]; tile
// 128x128, split-K x4 (K=1024 each), fp32 partials.
__global__ __launch_bounds__(256) void kv_kernel(
    const _Float16* __restrict__ vwT, const _Float16* __restrict__ krT,
    float* __restrict__ kvp) {
    __shared__ __align__(16) _Float16 As[128 * 32];
    __shared__ __align__(16) _Float16 Bs[128 * 32];
    const int tid = threadIdx.x, lane = tid & 63, wave = tid >> 6;
    const int quad = lane >> 4, l16 = lane & 15;
    const int wm = (wave >> 1) * 64, wn = (wave & 1) * 64;
    const int d0 = blockIdx.x * 128, e0 = blockIdx.y * 128;
    const int b = blockIdx.z >> 2, split = blockIdx.z & 3;
    const size_t base = (size_t)b * 512 * 4096;
    const int kbeg = split * 1024, kend = kbeg + 1024;
    const int ca = wave * 2;
    const int srow = lane >> 2, sseg = (lane & 3) * 8;
    f32x4 acc[4][4] = {};
    for (int k0 = kbeg; k0 < kend; k0 += 32) {
        #pragma unroll
        for (int c = 0; c < 2; c++) {
            int chunk = ca + c;
            int row = chunk * 16 + srow;
            gl_lds16(&vwT[base + (size_t)(e0 + row) * 4096 + k0 + sseg], &As[chunk * 512]);
            gl_lds16(&krT[base + (size_t)(d0 + row) * 4096 + k0 + sseg], &Bs[chunk * 512]);
        }
        __syncthreads();
        f16x8 af[4], bf[4];
        #pragma unroll
        for (int mi = 0; mi < 4; mi++)
            af[mi] = *(f16x8*)&As[(wm + mi * 16 + l16) * 32 + quad * 8];
        #pragma unroll
        for (int ni = 0; ni < 4; ni++)
            bf[ni] = *(f16x8*)&Bs[(wn + ni * 16 + l16) * 32 + quad * 8];
        #pragma unroll
        for (int mi = 0; mi < 4; mi++)
            #pragma unroll
            for (int ni = 0; ni < 4; ni++)
                acc[mi][ni] = __builtin_amdgcn_mfma_f32_16x16x32_f16(
                    af[mi], bf[ni], acc[mi][ni], 0, 0, 0);
        __syncthreads();
    }
    float* dst = kvp + ((size_t)split * 8 + b) * 262144;
    #pragma unroll
    for (int mi = 0; mi < 4; mi++)
        #pragma unroll
        for (int ni = 0; ni < 4; ni++)
            #pragma unroll
            for (int r = 0; r < 4; r++) {
                int e = e0 + wm + mi * 16 + quad * 4 + r;
                int d = d0 + wn + ni * 16 + l16;
                dst[e * 512 + d] = acc[mi][ni][r];
            }
}

// kvT[b][e][d] f16 = sum_s kvp[s][b][e][d]
__global__ __launch_bounds__(256) void reduce_kv(const float* __restrict__ kvp,
                                                 _Float16* __restrict__ kvT) {
    int i = (blockIdx.x * 256 + threadIdx.x) * 4;
    f32x4 s = *(const f32x4*)(kvp + i);
    s += *(const f32x4*)(kvp + 2097152 + i);
    s += *(const f32x4*)(kvp + 4194304 + i);
    s += *(const f32x4*)(kvp + 6291456 + i);
    f16x4 o = {(_Float16)s.x, (_Float16)s.y, (_Float16)s.z, (_Float16)s.w};
    *(f16x4*)(kvT + i) = o;
}

// ------------------------------------------------------------ out GEMM ----
// out[gm][e] = sum_d qr[gm][d] * kvT[b][e][d]; tile 128x128, BK=32.
__global__ __launch_bounds__(256) void out_kernel(
    const _Float16* __restrict__ qr, const _Float16* __restrict__ kvT,
    float* __restrict__ out) {
    __shared__ __align__(16) _Float16 As[128 * 32];
    __shared__ __align__(16) _Float16 Bs[128 * 32];
    const int tid = threadIdx.x, lane = tid & 63, wave = tid >> 6;
    const int quad = lane >> 4, l16 = lane & 15;
    const int wm = (wave >> 1) * 64, wn = (wave & 1) * 64;
    const int m0 = blockIdx.y * 128, e0 = blockIdx.x * 128;
    const int b = m0 >> 12;
    const int ca = wave * 2;
    const int srow = lane >> 2, sseg = (lane & 3) * 8;
    f32x4 acc[4][4] = {};
    for (int k0 = 0; k0 < 512; k0 += 32) {
        #pragma unroll
        for (int c = 0; c < 2; c++) {
            int chunk = ca + c;
            int row = chunk * 16 + srow;
            gl_lds16(&qr[(m0 + row) * 512 + k0 + sseg], &As[chunk * 512]);
            gl_lds16(&kvT[(size_t)b * 262144 + (e0 + row) * 512 + k0 + sseg],
                     &Bs[chunk * 512]);
        }
        __syncthreads();
        f16x8 af[4], bf[4];
        #pragma unroll
        for (int mi = 0; mi < 4; mi++)
            af[mi] = *(f16x8*)&As[(wm + mi * 16 + l16) * 32 + quad * 8];
        #pragma unroll
        for (int ni = 0; ni < 4; ni++)
            bf[ni] = *(f16x8*)&Bs[(wn + ni * 16 + l16) * 32 + quad * 8];
        #pragma unroll
        for (int mi = 0; mi < 4; mi++)
            #pragma unroll
            for (int ni = 0; ni < 4; ni++)
                acc[mi][ni] = __builtin_amdgcn_mfma_f32_16x16x32_f16(
                    af[mi], bf[ni], acc[mi][ni], 0, 0, 0);
        __syncthreads();
    }
    #pragma unroll
    for (int mi = 0; mi < 4; mi++)
        #pragma unroll
        for (int ni = 0; ni < 4; ni++)
            #pragma unroll
            for (int r = 0; r < 4; r++) {
                int gm = m0 + wm + mi * 16 + quad * 4 + r;
                int e = e0 + wn + ni * 16 + l16;
                out[(size_t)gm * 512 + e] = acc[mi][ni][r];
            }
}

// -------------------------------------------------------------- launch ----
extern "C" void kernel_launch(void* const* d_in, const int* in_sizes, int n_in,
                              void* d_out, int out_size, void* d_ws, size_t ws_size,
                              hipStream_t stream) {
    const float* phi     = (const float*)d_in[0];
    const float* coords  = (const float*)d_in[1];
    const float* weights = (const float*)d_in[2];
    const float* Wq      = (const float*)d_in[3];
    const float* bq      = (const float*)d_in[4];
    const float* Wk      = (const float*)d_in[5];
    const float* bk      = (const float*)d_in[6];
    const float* Wv      = (const float*)d_in[7];
    const float* bv      = (const float*)d_in[8];
    const float* Wrot    = (const float*)d_in[9];
    float* out = (float*)d_out;

    char* ws = (char*)d_ws;
    _Float16* phi_h = (_Float16*)(ws);
    float*    kvp   = (float*)   (ws);            // aliases phi_h (dead by then)
    _Float16* wcat  = (_Float16*)(ws + 33554432);
    float*    bcat  = (float*)   (ws + 35127296);
    _Float16* qr    = (_Float16*)(ws + 35133440);
    _Float16* krT   = (_Float16*)(ws + 68687872);
    _Float16* vwT   = (_Float16*)(ws + 102242304);
    _Float16* kvT   = (_Float16*)(ws + 135796736);  // end: 139,991,040 B

    convert_phi<<<16384, 256, 0, stream>>>(phi, phi_h);
    pack_w<<<1536, 256, 0, stream>>>(Wq, Wk, Wv, bq, bk, bv, wcat, bcat);
    qkv_kernel<<<dim3(12, 256), 256, 0, stream>>>(phi_h, wcat, bcat, coords,
                                                  weights, Wrot, qr, krT, vwT);
    kv_kernel<<<dim3(4, 4, 32), 256, 0, stream>>>(vwT, krT, kvp);
    reduce_kv<<<2048, 256, 0, stream>>>(kvp, kvT);
    out_kernel<<<dim3(4, 256), 256, 0, stream>>>(qr, kvT, out);
}

// Round 3
// 319.710 us; speedup vs baseline: 1.1134x; 1.0207x over previous
//
#include <hip/hip_runtime.h>

// LinearSelfAttention: out = rot(q) @ (rot(k)^T @ (w*v)), fp16 MFMA.
// Round 3: single-barrier double-buffered K-loops (prefetch via
// global_load_lds overlaps MFMA), kv split-K x8 with f16 partials.
//
// ws layout (~133.5 MiB):
//   phi_h  [32768][512] f16   @ 0            (33,554,432 B)  } kvp f16[8] aliases
//   wcat   [1536][512]  f16   @ 33,554,432   ( 1,572,864 B)    phi_h after qkv
//   bcat   [1536]       f32   @ 35,127,296   (     6,144 B)
//   qr     [32768][512] f16   @ 35,133,440   (33,554,432 B)
//   krT    [8][512][4096] f16 @ 68,687,872   (33,554,432 B)
//   vwT    [8][512][4096] f16 @ 102,242,304  (33,554,432 B)
//   kvT    [8][512][512] f16  @ 135,796,736  ( 4,194,304 B)

typedef _Float16 f16x8 __attribute__((ext_vector_type(8)));
typedef _Float16 f16x4 __attribute__((ext_vector_type(4)));
typedef float f32x4 __attribute__((ext_vector_type(4)));

__device__ __forceinline__ void gl_lds16(const void* g, void* l) {
    __builtin_amdgcn_global_load_lds(
        (const __attribute__((address_space(1))) void*)g,
        (__attribute__((address_space(3))) void*)l, 16, 0, 0);
}

// Stage one 128x32 A-tile and B-tile (BK=32) into LDS. gA/gB point at
// (tile_row0, k0). Each wave fills 2 chunks of 16 rows per operand.
__device__ __forceinline__ void stage2(const _Float16* gA, size_t sA,
                                       const _Float16* gB, size_t sB,
                                       _Float16* As, _Float16* Bs,
                                       int ca, int srow, int sseg) {
    gl_lds16(&gA[(size_t)(ca * 16 + srow) * sA + sseg], &As[ca * 512]);
    gl_lds16(&gA[(size_t)(ca * 16 + 16 + srow) * sA + sseg], &As[(ca + 1) * 512]);
    gl_lds16(&gB[(size_t)(ca * 16 + srow) * sB + sseg], &Bs[ca * 512]);
    gl_lds16(&gB[(size_t)(ca * 16 + 16 + srow) * sB + sseg], &Bs[(ca + 1) * 512]);
}

// One BK=32 MFMA step from LDS tiles (4 waves, 64x64 per wave, 4x4 16x16).
__device__ __forceinline__ void mfma_step(const _Float16* As, const _Float16* Bs,
                                          int wm, int wn, int l16, int quad,
                                          f32x4 acc[4][4]) {
    f16x8 af[4], bf[4];
    #pragma unroll
    for (int mi = 0; mi < 4; mi++)
        af[mi] = *(const f16x8*)&As[(wm + mi * 16 + l16) * 32 + quad * 8];
    #pragma unroll
    for (int ni = 0; ni < 4; ni++)
        bf[ni] = *(const f16x8*)&Bs[(wn + ni * 16 + l16) * 32 + quad * 8];
    #pragma unroll
    for (int mi = 0; mi < 4; mi++)
        #pragma unroll
        for (int ni = 0; ni < 4; ni++)
            acc[mi][ni] = __builtin_amdgcn_mfma_f32_16x16x32_f16(
                af[mi], bf[ni], acc[mi][ni], 0, 0, 0);
}

// ---------------------------------------------------------------- prep ----
__global__ __launch_bounds__(256) void convert_phi(const float* __restrict__ phi,
                                                   _Float16* __restrict__ phi_h) {
    int i = (blockIdx.x * 256 + threadIdx.x) * 4;
    float4 v = *(const float4*)(phi + i);
    f16x4 o = {(_Float16)v.x, (_Float16)v.y, (_Float16)v.z, (_Float16)v.w};
    *(f16x4*)(phi_h + i) = o;
}

__global__ __launch_bounds__(256) void pack_w(
    const float* __restrict__ Wq, const float* __restrict__ Wk,
    const float* __restrict__ Wv, const float* __restrict__ bq,
    const float* __restrict__ bk, const float* __restrict__ bv,
    _Float16* __restrict__ wcat, float* __restrict__ bcat) {
    int j = blockIdx.x;            // 0..1535 output row
    int reg = j >> 9, jr = j & 511;
    const float* W; const float* bias;
    if (reg == 0)      { W = Wq; bias = bq; }
    else if (reg == 1) { W = Wk; bias = bk; }
    else               { W = Wv; bias = bv; }
    int d = (reg < 2) ? ((jr & 1) ? (jr >> 1) + 256 : (jr >> 1)) : jr;
    for (int i = threadIdx.x; i < 512; i += 256)
        wcat[j * 512 + i] = (_Float16)W[d * 512 + i];
    if (threadIdx.x == 0) bcat[j] = bias[d];
}

// ------------------------------------------------------------ QKV GEMM ----
// C[32768][1536] = phi_h @ wcat^T, tile 128x128, dbuf BK=32.
__global__ __launch_bounds__(256) void qkv_kernel(
    const _Float16* __restrict__ phi_h, const _Float16* __restrict__ wcat,
    const float* __restrict__ bcat, const float* __restrict__ coords,
    const float* __restrict__ weights, const float* __restrict__ Wrot,
    _Float16* __restrict__ qr, _Float16* __restrict__ krT,
    _Float16* __restrict__ vwT) {
    __shared__ __align__(16) char smem[34816];          // Ts 128x136 f16 alias
    _Float16* As0 = (_Float16*)smem;
    _Float16* Bs0 = (_Float16*)(smem + 8192);
    _Float16* As1 = (_Float16*)(smem + 16384);
    _Float16* Bs1 = (_Float16*)(smem + 24576);
    _Float16* Ts  = (_Float16*)smem;

    const int tid = threadIdx.x;
    const int lane = tid & 63, wave = tid >> 6;
    const int quad = lane >> 4, l16 = lane & 15;
    const int wm = (wave >> 1) * 64, wn = (wave & 1) * 64;
    const int m0 = blockIdx.y * 128;      // row tile (over B*N)
    const int c0 = blockIdx.x * 128;      // col tile (over 1536)
    const int ca = wave * 2;
    const int srow = lane >> 2, sseg = (lane & 3) * 8;

    const _Float16* gA = phi_h + (size_t)m0 * 512;
    const _Float16* gB = wcat + (size_t)c0 * 512;

    f32x4 acc[4][4] = {};

    stage2(gA, 512, gB, 512, As0, Bs0, ca, srow, sseg);
    __syncthreads();
    for (int k0 = 0; k0 < 512; k0 += 64) {
        stage2(gA + k0 + 32, 512, gB + k0 + 32, 512, As1, Bs1, ca, srow, sseg);
        mfma_step(As0, Bs0, wm, wn, l16, quad, acc);
        __syncthreads();
        if (k0 + 64 < 512)
            stage2(gA + k0 + 64, 512, gB + k0 + 64, 512, As0, Bs0, ca, srow, sseg);
        mfma_step(As1, Bs1, wm, wn, l16, quad, acc);
        __syncthreads();
    }

    const int region = c0 >> 9;   // 0=q, 1=k, 2=v (128 | 512: never straddles)
    const float qscale = 0.04419417382415922f;  // 1/sqrt(512)

    float bias[4], w0[4], w1[4], w2[4];
    #pragma unroll
    for (int ni = 0; ni < 4; ni++) {
        int gc = c0 + wn + ni * 16 + l16;
        bias[ni] = bcat[gc];
        if (region < 2) {
            int jp = (gc & 511) >> 1;
            w0[ni] = Wrot[jp * 3];
            w1[ni] = Wrot[jp * 3 + 1];
            w2[ni] = Wrot[jp * 3 + 2];
        }
    }

    if (region == 0) {
        // q: rotary + scale -> Ts[row][col] -> coalesced qr store
        #pragma unroll
        for (int mi = 0; mi < 4; mi++)
            #pragma unroll
            for (int r = 0; r < 4; r++) {
                int row = wm + mi * 16 + quad * 4 + r;
                int gm = m0 + row;
                float x = coords[gm * 3], y = coords[gm * 3 + 1], z = coords[gm * 3 + 2];
                #pragma unroll
                for (int ni = 0; ni < 4; ni++) {
                    float val = (acc[mi][ni][r] + bias[ni]) * qscale;
                    float part = __shfl_xor(val, 1);
                    float ph = x * w0[ni] + y * w1[ni] + z * w2[ni];
                    float sv, cv; __sincosf(ph, &sv, &cv);
                    float res = (l16 & 1) ? (part * sv + val * cv)
                                          : (val * cv - part * sv);
                    Ts[row * 136 + wn + ni * 16 + l16] = (_Float16)res;
                }
            }
        __syncthreads();
        for (int i = tid; i < 2048; i += 256) {
            int row = i >> 4, cv = (i & 15) * 8;
            *(f16x8*)&qr[(m0 + row) * 512 + c0 + cv] = *(f16x8*)&Ts[row * 136 + cv];
        }
    } else {
        // k: rotary; v: *weights. -> Ts[col][row] -> coalesced [b][col][n]
        #pragma unroll
        for (int mi = 0; mi < 4; mi++)
            #pragma unroll
            for (int r = 0; r < 4; r++) {
                int row = wm + mi * 16 + quad * 4 + r;
                int gm = m0 + row;
                if (region == 1) {
                    float x = coords[gm * 3], y = coords[gm * 3 + 1], z = coords[gm * 3 + 2];
                    #pragma unroll
                    for (int ni = 0; ni < 4; ni++) {
                        float val = acc[mi][ni][r] + bias[ni];
                        float part = __shfl_xor(val, 1);
                        float ph = x * w0[ni] + y * w1[ni] + z * w2[ni];
                        float sv, cv; __sincosf(ph, &sv, &cv);
                        float res = (l16 & 1) ? (part * sv + val * cv)
                                              : (val * cv - part * sv);
                        Ts[(wn + ni * 16 + l16) * 136 + row] = (_Float16)res;
                    }
                } else {
                    float wgt = weights[gm];
                    #pragma unroll
                    for (int ni = 0; ni < 4; ni++) {
                        float val = (acc[mi][ni][r] + bias[ni]) * wgt;
                        Ts[(wn + ni * 16 + l16) * 136 + row] = (_Float16)val;
                    }
                }
            }
        __syncthreads();
        _Float16* dst = (region == 1) ? krT : vwT;
        const int b = m0 >> 12, n0 = m0 & 4095, cb = c0 & 511;
        for (int i = tid; i < 2048; i += 256) {
            int col = i >> 4, rv = (i & 15) * 8;
            *(f16x8*)&dst[((size_t)b * 512 + cb + col) * 4096 + n0 + rv] =
                *(f16x8*)&Ts[col * 136 + rv];
        }
    }
}

// ------------------------------------------------------------- kv GEMM ----
// kvp[s][b][e][d] (f16) = sum_{n in split s} vwT[b][e][n]*krT[b][d][n];
// tile 128x128, split-K x8 (K=512 each), dbuf BK=32.
__global__ __launch_bounds__(256) void kv_kernel(
    const _Float16* __restrict__ vwT, const _Float16* __restrict__ krT,
    _Float16* __restrict__ kvp) {
    __shared__ __align__(16) char smem[32768];
    _Float16* As0 = (_Float16*)smem;
    _Float16* Bs0 = (_Float16*)(smem + 8192);
    _Float16* As1 = (_Float16*)(smem + 16384);
    _Float16* Bs1 = (_Float16*)(smem + 24576);
    const int tid = threadIdx.x, lane = tid & 63, wave = tid >> 6;
    const int quad = lane >> 4, l16 = lane & 15;
    const int wm = (wave >> 1) * 64, wn = (wave & 1) * 64;
    const int d0 = blockIdx.x * 128, e0 = blockIdx.y * 128;
    const int b = blockIdx.z >> 3, split = blockIdx.z & 7;
    const int ca = wave * 2;
    const int srow = lane >> 2, sseg = (lane & 3) * 8;
    const size_t base = (size_t)b * 512 * 4096;
    const int kbeg = split * 512;
    const _Float16* gA = vwT + base + (size_t)e0 * 4096 + kbeg;
    const _Float16* gB = krT + base + (size_t)d0 * 4096 + kbeg;
    f32x4 acc[4][4] = {};

    stage2(gA, 4096, gB, 4096, As0, Bs0, ca, srow, sseg);
    __syncthreads();
    for (int k0 = 0; k0 < 512; k0 += 64) {
        stage2(gA + k0 + 32, 4096, gB + k0 + 32, 4096, As1, Bs1, ca, srow, sseg);
        mfma_step(As0, Bs0, wm, wn, l16, quad, acc);
        __syncthreads();
        if (k0 + 64 < 512)
            stage2(gA + k0 + 64, 4096, gB + k0 + 64, 4096, As0, Bs0, ca, srow, sseg);
        mfma_step(As1, Bs1, wm, wn, l16, quad, acc);
        __syncthreads();
    }

    _Float16* dst = kvp + ((size_t)split * 8 + b) * 262144;
    #pragma unroll
    for (int mi = 0; mi < 4; mi++)
        #pragma unroll
        for (int ni = 0; ni < 4; ni++)
            #pragma unroll
            for (int r = 0; r < 4; r++) {
                int e = e0 + wm + mi * 16 + quad * 4 + r;
                int d = d0 + wn + ni * 16 + l16;
                dst[e * 512 + d] = (_Float16)acc[mi][ni][r];
            }
}

// kvT[b][e][d] f16 = sum_s kvp[s][b][e][d]
__global__ __launch_bounds__(256) void reduce_kv(const _Float16* __restrict__ kvp,
                                                 _Float16* __restrict__ kvT) {
    int i = (blockIdx.x * 256 + threadIdx.x) * 8;
    float s[8] = {};
    #pragma unroll
    for (int sp = 0; sp < 8; sp++) {
        f16x8 v = *(const f16x8*)(kvp + (size_t)sp * 2097152 + i);
        #pragma unroll
        for (int j = 0; j < 8; j++) s[j] += (float)v[j];
    }
    f16x8 o;
    #pragma unroll
    for (int j = 0; j < 8; j++) o[j] = (_Float16)s[j];
    *(f16x8*)(kvT + i) = o;
}

// ------------------------------------------------------------ out GEMM ----
// out[gm][e] = sum_d qr[gm][d] * kvT[b][e][d]; tile 128x128, dbuf BK=32.
__global__ __launch_bounds__(256) void out_kernel(
    const _Float16* __restrict__ qr, const _Float16* __restrict__ kvT,
    float* __restrict__ out) {
    __shared__ __align__(16) char smem[32768];
    _Float16* As0 = (_Float16*)smem;
    _Float16* Bs0 = (_Float16*)(smem + 8192);
    _Float16* As1 = (_Float16*)(smem + 16384);
    _Float16* Bs1 = (_Float16*)(smem + 24576);
    const int tid = threadIdx.x, lane = tid & 63, wave = tid >> 6;
    const int quad = lane >> 4, l16 = lane & 15;
    const int wm = (wave >> 1) * 64, wn = (wave & 1) * 64;
    const int m0 = blockIdx.y * 128, e0 = blockIdx.x * 128;
    const int b = m0 >> 12;
    const int ca = wave * 2;
    const int srow = lane >> 2, sseg = (lane & 3) * 8;
    const _Float16* gA = qr + (size_t)m0 * 512;
    const _Float16* gB = kvT + (size_t)b * 262144 + (size_t)e0 * 512;
    f32x4 acc[4][4] = {};

    stage2(gA, 512, gB, 512, As0, Bs0, ca, srow, sseg);
    __syncthreads();
    for (int k0 = 0; k0 < 512; k0 += 64) {
        stage2(gA + k0 + 32, 512, gB + k0 + 32, 512, As1, Bs1, ca, srow, sseg);
        mfma_step(As0, Bs0, wm, wn, l16, quad, acc);
        __syncthreads();
        if (k0 + 64 < 512)
            stage2(gA + k0 + 64, 512, gB + k0 + 64, 512, As0, Bs0, ca, srow, sseg);
        mfma_step(As1, Bs1, wm, wn, l16, quad, acc);
        __syncthreads();
    }

    #pragma unroll
    for (int mi = 0; mi < 4; mi++)
        #pragma unroll
        for (int ni = 0; ni < 4; ni++)
            #pragma unroll
            for (int r = 0; r < 4; r++) {
                int gm = m0 + wm + mi * 16 + quad * 4 + r;
                int e = e0 + wn + ni * 16 + l16;
                out[(size_t)gm * 512 + e] = acc[mi][ni][r];
            }
}

// -------------------------------------------------------------- launch ----
extern "C" void kernel_launch(void* const* d_in, const int* in_sizes, int n_in,
                              void* d_out, int out_size, void* d_ws, size_t ws_size,
                              hipStream_t stream) {
    const float* phi     = (const float*)d_in[0];
    const float* coords  = (const float*)d_in[1];
    const float* weights = (const float*)d_in[2];
    const float* Wq      = (const float*)d_in[3];
    const float* bq      = (const float*)d_in[4];
    const float* Wk      = (const float*)d_in[5];
    const float* bk      = (const float*)d_in[6];
    const float* Wv      = (const float*)d_in[7];
    const float* bv      = (const float*)d_in[8];
    const float* Wrot    = (const float*)d_in[9];
    float* out = (float*)d_out;

    char* ws = (char*)d_ws;
    _Float16* phi_h = (_Float16*)(ws);
    _Float16* kvp   = (_Float16*)(ws);            // aliases phi_h (dead by then)
    _Float16* wcat  = (_Float16*)(ws + 33554432);
    float*    bcat  = (float*)   (ws + 35127296);
    _Float16* qr    = (_Float16*)(ws + 35133440);
    _Float16* krT   = (_Float16*)(ws + 68687872);
    _Float16* vwT   = (_Float16*)(ws + 102242304);
    _Float16* kvT   = (_Float16*)(ws + 135796736);  // end: 139,991,040 B

    convert_phi<<<16384, 256, 0, stream>>>(phi, phi_h);
    pack_w<<<1536, 256, 0, stream>>>(Wq, Wk, Wv, bq, bk, bv, wcat, bcat);
    qkv_kernel<<<dim3(12, 256), 256, 0, stream>>>(phi_h, wcat, bcat, coords,
                                                  weights, Wrot, qr, krT, vwT);
    kv_kernel<<<dim3(4, 4, 64), 256, 0, stream>>>(vwT, krT, kvp);
    reduce_kv<<<1024, 256, 0, stream>>>(kvp, kvT);
    out_kernel<<<dim3(4, 256), 256, 0, stream>>>(qr, kvT, out);
}